// Round 15
// baseline (84.387 us; speedup 1.0000x reference)
//
#include <hip/hip_runtime.h>

#define BB 16
#define CIN 256
#define COUT 128
#define EE 512
#define HH 64
#define WW 64
#define HP 66   // padded spatial dim
#define NCG 16  // CIN/16 chunks of 16 i8

typedef int v4i __attribute__((ext_vector_type(4)));
typedef int v16i __attribute__((ext_vector_type(16)));

// ws layout (bytes):
//   bias1 [16][256] f32 @ 0        (16384)
//   bias2 [16][128] f32 @ 16384    (8192)
//   bias3 [16][128] f32 @ 24576    (8192)
//   A     [128] f32     @ 33280    (512)
//   B0    [128] f32     @ 33792    (512)
//   Wt2   [9][16][128]x16B @ 34304 (294912)    (tap, c-chunk, o)
//   S2    [16][66][16][66]x16B @ 329216 (17842176)  (b, row, c-chunk, col)

__global__ __launch_bounds__(256) void prep2_k(
    const float* __restrict__ emb,
    const float* __restrict__ m1w, const float* __restrict__ m1b,
    const float* __restrict__ m2w, const float* __restrict__ m2b,
    const float* __restrict__ m3w, const float* __restrict__ m3b,
    const float* __restrict__ conv_w, const float* __restrict__ conv_b,
    const float* __restrict__ bn_g, const float* __restrict__ bn_b,
    const float* __restrict__ bn_m, const float* __restrict__ bn_v,
    float* __restrict__ bias1, float* __restrict__ bias2, float* __restrict__ bias3,
    float* __restrict__ A, float* __restrict__ B0,
    signed char* __restrict__ Wt)
{
    int bid = blockIdx.x;
    int tid = threadIdx.x;
    __shared__ float red[256];
    if (bid < 128) {
        int b = bid >> 3;
        int chunk = bid & 7;
        __shared__ float se[EE];
        {
            float v0 = emb[b * EE + tid];
            float v1 = emb[b * EE + tid + 256];
            se[tid] = v0 / (1.0f + __expf(-v0));
            se[tid + 256] = v1 / (1.0f + __expf(-v1));
        }
        __syncthreads();
        int cl = tid & 63;
        int ks = tid >> 6;
        const float* W;
        const float* Bv;
        float* dst;
        int c0;
        if (chunk < 4)      { c0 = chunk * 64;       W = m1w; Bv = m1b; dst = bias1 + b * CIN + c0; }
        else if (chunk < 6) { c0 = (chunk - 4) * 64; W = m2w; Bv = m2b; dst = bias2 + b * COUT + c0; }
        else                { c0 = (chunk - 6) * 64; W = m3w; Bv = m3b; dst = bias3 + b * COUT + c0; }
        const float4* w4 = (const float4*)(W + (size_t)(c0 + cl) * EE + ks * 128);
        const float* sp = &se[ks * 128];
        float acc = 0.f;
        #pragma unroll
        for (int e4 = 0; e4 < 32; ++e4) {
            float4 v = w4[e4];
            acc += sp[e4 * 4 + 0] * v.x + sp[e4 * 4 + 1] * v.y +
                   sp[e4 * 4 + 2] * v.z + sp[e4 * 4 + 3] * v.w;
        }
        red[tid] = acc;
        __syncthreads();
        if (ks == 0)
            dst[cl] = red[cl] + red[cl + 64] + red[cl + 128] + red[cl + 192] + Bv[c0 + cl];
    } else {
        int o = bid - 128;
        int c = tid;
        float wv[9];
        float asum = 0.f;
        const float* wp = conv_w + ((size_t)o * CIN + c) * 9;
        #pragma unroll
        for (int k = 0; k < 9; ++k) {
            float v = wp[k];
            wv[k] = v;
            asum += fabsf(v);
        }
        #pragma unroll
        for (int k = 0; k < 9; ++k)
            Wt[(((size_t)k * NCG + (c >> 4)) * COUT + o) * 16 + (c & 15)] =
                (wv[k] > 0.f) ? (signed char)1 : (signed char)-1;
        red[tid] = asum;
        __syncthreads();
        for (int s = 128; s > 0; s >>= 1) {
            if (tid < s) red[tid] += red[tid + s];
            __syncthreads();
        }
        if (tid == 0) {
            float sc = red[0] * (1.0f / 2304.0f);
            float inv = bn_g[o] * rsqrtf(bn_v[o] + 1e-5f);
            A[o] = sc * inv;
            B0[o] = (conv_b[o] - bn_m[o]) * inv + bn_b[o];
        }
    }
}

// 1024 blocks (b*64+h), 256 threads = 64 w x 4 q-groups; q handles 4 c-chunks.
__global__ __launch_bounds__(256) void sign_k(
    const float* __restrict__ x, const float* __restrict__ bias1,
    signed char* __restrict__ S)
{
    __shared__ float sb[CIN];
    int bid = blockIdx.x;
    int b = bid >> 6;
    int h = bid & 63;
    int tid = threadIdx.x;

    // halo zeroing: 16 b * 260 ring cells * 16 cg = 66560 16-B chunks
    if (bid < 260) {
        int hidx = bid * 256 + tid;   // exactly 260*256 = 66560
        int cellg = hidx >> 4;
        int cg = hidx & 15;
        int b2 = cellg / 260;
        int rem = cellg % 260;
        int r, col;
        if (rem < 66)       { r = 0;  col = rem; }
        else if (rem < 132) { r = 65; col = rem - 66; }
        else                { int c2 = rem - 132; r = 1 + (c2 >> 1); col = (c2 & 1) * 65; }
        int4 z = make_int4(0, 0, 0, 0);
        *(int4*)(S + ((((size_t)b2 * HP + r) * NCG + cg) * HP + col) * 16) = z;
    }

    sb[tid] = bias1[b * CIN + tid];
    __syncthreads();

    int w = tid & 63;
    int q = tid >> 6;
    const float* xp = x + (size_t)b * CIN * (HH * WW) + (size_t)h * WW + w;
    #pragma unroll
    for (int st = 0; st < 4; ++st) {
        int cg = q * 4 + st;
        unsigned int pk0 = 0, pk1 = 0, pk2 = 0, pk3 = 0;
        #pragma unroll
        for (int j = 0; j < 4; ++j) {
            int c = cg * 16 + j;
            float t0 = xp[(size_t)(c +  0) * (HH * WW)] + sb[c +  0];
            float t1 = xp[(size_t)(c +  4) * (HH * WW)] + sb[c +  4];
            float t2 = xp[(size_t)(c +  8) * (HH * WW)] + sb[c +  8];
            float t3 = xp[(size_t)(c + 12) * (HH * WW)] + sb[c + 12];
            pk0 |= (t0 > 0.f ? 0x01u : 0xFFu) << (8 * j);
            pk1 |= (t1 > 0.f ? 0x01u : 0xFFu) << (8 * j);
            pk2 |= (t2 > 0.f ? 0x01u : 0xFFu) << (8 * j);
            pk3 |= (t3 > 0.f ? 0x01u : 0xFFu) << (8 * j);
        }
        int4 val = make_int4((int)pk0, (int)pk1, (int)pk2, (int)pk3);
        *(int4*)(S + ((((size_t)b * HP + (h + 1)) * NCG + cg) * HP + (w + 1)) * 16) = val;
    }
}

// 1024 blocks (b*64+h), 512 threads = 8 waves = (om in 4) x (ph in 2).
// Each wave: ONE 32x32 C-tile (o = om*32.., w = ph*32..), 72 k-steps.
// Same per-block traffic as R13, but 24 waves/CU (vs 7) for latency hiding.
__global__ __launch_bounds__(512, 6) void main2_k(
    const signed char* __restrict__ Wt,    // [9][16][128]x16B
    const signed char* __restrict__ S,     // [16][66][16][66]x16B
    const float* __restrict__ x,
    const float* __restrict__ A, const float* __restrict__ B0,
    const float* __restrict__ bias2, const float* __restrict__ bias3,
    const float* __restrict__ prelu_a,
    float* __restrict__ out)
{
    __shared__ v4i Sl[3 * NCG * HP];   // 50688 B
    int bid = blockIdx.x;
    int b = bid >> 6;
    int h = bid & 63;
    int tid = threadIdx.x;
    int l = tid & 63;
    int wid = tid >> 6;      // 0..7
    int om = wid & 3;        // o-tile
    int ph = wid >> 2;       // pixel half
    int lr = l & 31;
    int lk = l >> 5;

    // stage rows h..h+2 (contiguous 50688 B in S)
    {
        const v4i* src = (const v4i*)(S + (((size_t)b * HP + h) * NCG) * (size_t)HP * 16);
        #pragma unroll
        for (int i = 0; i < 7; ++i) {
            int idx = tid + i * 512;
            if (idx < 3 * NCG * HP) Sl[idx] = src[idx];
        }
    }
    __syncthreads();

    v16i acca = {}, accb = {};

    const signed char* abase = Wt + ((size_t)lk * COUT + om * 32 + lr) * 16;

    #pragma unroll
    for (int t = 0; t < 9; ++t) {
        const int r = t / 3, dw = t % 3;
        const signed char* ap = abase + (size_t)t * NCG * COUT * 16;
        const v4i* bl = &Sl[(r * NCG + lk) * HP + dw + ph * 32 + lr];
        #pragma unroll
        for (int ck = 0; ck < 8; ++ck) {
            v4i a  = *(const v4i*)(ap + (size_t)ck * 2 * COUT * 16);
            v4i bv = bl[ck * 2 * HP];
            if (ck & 1) accb = __builtin_amdgcn_mfma_i32_32x32x32_i8(a, bv, accb, 0, 0, 0);
            else        acca = __builtin_amdgcn_mfma_i32_32x32x32_i8(a, bv, acca, 0, 0, 0);
        }
    }

    v16i acc = acca + accb;

    #pragma unroll
    for (int g = 0; g < 16; ++g) {
        int o = om * 32 + (g & 3) + 8 * (g >> 2) + 4 * lk;
        int w = ph * 32 + lr;
        float Ao = A[o], B0o = B0[o];
        float b2 = bias2[b * COUT + o], b3 = bias3[b * COUT + o], pa = prelu_a[o];
        const float* xr = x + ((size_t)(b * CIN + 2 * o)) * (HH * WW) + (size_t)h * WW;
        float cv = (float)acc[g] * Ao + B0o;
        float r0 = xr[w], r1 = xr[HH * WW + w];
        float tv = cv + 0.5f * (r0 + r1) + b2;
        tv = tv > 0.f ? tv : pa * tv;
        out[((size_t)(b * COUT + o)) * (HH * WW) + (size_t)h * WW + w] = tv + b3;
    }
}

extern "C" void kernel_launch(void* const* d_in, const int* in_sizes, int n_in,
                              void* d_out, int out_size, void* d_ws, size_t ws_size,
                              hipStream_t stream) {
    const float* x      = (const float*)d_in[0];
    const float* emb    = (const float*)d_in[1];
    const float* m1w    = (const float*)d_in[2];
    const float* m1b    = (const float*)d_in[3];
    const float* conv_w = (const float*)d_in[4];
    const float* conv_b = (const float*)d_in[5];
    const float* bn_g   = (const float*)d_in[6];
    const float* bn_b   = (const float*)d_in[7];
    const float* bn_m   = (const float*)d_in[8];
    const float* bn_v   = (const float*)d_in[9];
    const float* m2w    = (const float*)d_in[10];
    const float* m2b    = (const float*)d_in[11];
    const float* pa     = (const float*)d_in[12];
    const float* m3w    = (const float*)d_in[13];
    const float* m3b    = (const float*)d_in[14];
    float* out = (float*)d_out;

    char* ws = (char*)d_ws;
    float* bias1 = (float*)(ws + 0);
    float* bias2 = (float*)(ws + 16384);
    float* bias3 = (float*)(ws + 24576);
    float* Aarr  = (float*)(ws + 33280);
    float* B0arr = (float*)(ws + 33792);
    signed char* Wt = (signed char*)(ws + 34304);
    signed char* S  = (signed char*)(ws + 329216);

    prep2_k<<<256, 256, 0, stream>>>(emb, m1w, m1b, m2w, m2b, m3w, m3b,
                                     conv_w, conv_b, bn_g, bn_b, bn_m, bn_v,
                                     bias1, bias2, bias3, Aarr, B0arr, Wt);
    sign_k<<<BB * HH, 256, 0, stream>>>(x, bias1, S);
    main2_k<<<BB * HH, 512, 0, stream>>>(Wt, S, x, Aarr, B0arr,
                                         bias2, bias3, pa, out);
}

// Round 16
// 66.483 us; speedup vs baseline: 1.2693x; 1.2693x over previous
//
#include <hip/hip_runtime.h>

#define BB 16
#define CIN 256
#define COUT 128
#define EE 512
#define HH 64
#define WW 64
#define HP 66   // padded spatial dim
#define NCG 16  // CIN/16 chunks of 16 i8

typedef int v4i __attribute__((ext_vector_type(4)));
typedef int v16i __attribute__((ext_vector_type(16)));

// ws layout (bytes):
//   bias1 [16][256] f32 @ 0        (16384)
//   bias2 [16][128] f32 @ 16384    (8192)
//   bias3 [16][128] f32 @ 24576    (8192)
//   A     [128] f32     @ 33280    (512)
//   B0    [128] f32     @ 33792    (512)
//   Wt2   [9][16][128]x16B @ 34304 (294912)    (tap, c-chunk, o)
//   S2    [16][66][16][66]x16B @ 329216 (17842176)  (b, row, c-chunk, col)

__global__ __launch_bounds__(256) void prep2_k(
    const float* __restrict__ emb,
    const float* __restrict__ m1w, const float* __restrict__ m1b,
    const float* __restrict__ m2w, const float* __restrict__ m2b,
    const float* __restrict__ m3w, const float* __restrict__ m3b,
    const float* __restrict__ conv_w, const float* __restrict__ conv_b,
    const float* __restrict__ bn_g, const float* __restrict__ bn_b,
    const float* __restrict__ bn_m, const float* __restrict__ bn_v,
    float* __restrict__ bias1, float* __restrict__ bias2, float* __restrict__ bias3,
    float* __restrict__ A, float* __restrict__ B0,
    signed char* __restrict__ Wt)
{
    int bid = blockIdx.x;
    int tid = threadIdx.x;
    __shared__ float red[256];
    if (bid < 128) {
        int b = bid >> 3;
        int chunk = bid & 7;
        __shared__ float se[EE];
        {
            float v0 = emb[b * EE + tid];
            float v1 = emb[b * EE + tid + 256];
            se[tid] = v0 / (1.0f + __expf(-v0));
            se[tid + 256] = v1 / (1.0f + __expf(-v1));
        }
        __syncthreads();
        int cl = tid & 63;
        int ks = tid >> 6;
        const float* W;
        const float* Bv;
        float* dst;
        int c0;
        if (chunk < 4)      { c0 = chunk * 64;       W = m1w; Bv = m1b; dst = bias1 + b * CIN + c0; }
        else if (chunk < 6) { c0 = (chunk - 4) * 64; W = m2w; Bv = m2b; dst = bias2 + b * COUT + c0; }
        else                { c0 = (chunk - 6) * 64; W = m3w; Bv = m3b; dst = bias3 + b * COUT + c0; }
        const float4* w4 = (const float4*)(W + (size_t)(c0 + cl) * EE + ks * 128);
        const float* sp = &se[ks * 128];
        float acc = 0.f;
        #pragma unroll
        for (int e4 = 0; e4 < 32; ++e4) {
            float4 v = w4[e4];
            acc += sp[e4 * 4 + 0] * v.x + sp[e4 * 4 + 1] * v.y +
                   sp[e4 * 4 + 2] * v.z + sp[e4 * 4 + 3] * v.w;
        }
        red[tid] = acc;
        __syncthreads();
        if (ks == 0)
            dst[cl] = red[cl] + red[cl + 64] + red[cl + 128] + red[cl + 192] + Bv[c0 + cl];
    } else {
        int o = bid - 128;
        int c = tid;
        float wv[9];
        float asum = 0.f;
        const float* wp = conv_w + ((size_t)o * CIN + c) * 9;
        #pragma unroll
        for (int k = 0; k < 9; ++k) {
            float v = wp[k];
            wv[k] = v;
            asum += fabsf(v);
        }
        #pragma unroll
        for (int k = 0; k < 9; ++k)
            Wt[(((size_t)k * NCG + (c >> 4)) * COUT + o) * 16 + (c & 15)] =
                (wv[k] > 0.f) ? (signed char)1 : (signed char)-1;
        red[tid] = asum;
        __syncthreads();
        for (int s = 128; s > 0; s >>= 1) {
            if (tid < s) red[tid] += red[tid + s];
            __syncthreads();
        }
        if (tid == 0) {
            float sc = red[0] * (1.0f / 2304.0f);
            float inv = bn_g[o] * rsqrtf(bn_v[o] + 1e-5f);
            A[o] = sc * inv;
            B0[o] = (conv_b[o] - bn_m[o]) * inv + bn_b[o];
        }
    }
}

// 1024 blocks (b*64+h), 256 threads = 64 w x 4 q-groups; q handles 4 c-chunks.
__global__ __launch_bounds__(256) void sign_k(
    const float* __restrict__ x, const float* __restrict__ bias1,
    signed char* __restrict__ S)
{
    __shared__ float sb[CIN];
    int bid = blockIdx.x;
    int b = bid >> 6;
    int h = bid & 63;
    int tid = threadIdx.x;

    // halo zeroing: 16 b * 260 ring cells * 16 cg = 66560 16-B chunks
    if (bid < 260) {
        int hidx = bid * 256 + tid;   // exactly 260*256 = 66560
        int cellg = hidx >> 4;
        int cg = hidx & 15;
        int b2 = cellg / 260;
        int rem = cellg % 260;
        int r, col;
        if (rem < 66)       { r = 0;  col = rem; }
        else if (rem < 132) { r = 65; col = rem - 66; }
        else                { int c2 = rem - 132; r = 1 + (c2 >> 1); col = (c2 & 1) * 65; }
        int4 z = make_int4(0, 0, 0, 0);
        *(int4*)(S + ((((size_t)b2 * HP + r) * NCG + cg) * HP + col) * 16) = z;
    }

    sb[tid] = bias1[b * CIN + tid];
    __syncthreads();

    int w = tid & 63;
    int q = tid >> 6;
    const float* xp = x + (size_t)b * CIN * (HH * WW) + (size_t)h * WW + w;
    #pragma unroll
    for (int st = 0; st < 4; ++st) {
        int cg = q * 4 + st;
        unsigned int pk0 = 0, pk1 = 0, pk2 = 0, pk3 = 0;
        #pragma unroll
        for (int j = 0; j < 4; ++j) {
            int c = cg * 16 + j;
            float t0 = xp[(size_t)(c +  0) * (HH * WW)] + sb[c +  0];
            float t1 = xp[(size_t)(c +  4) * (HH * WW)] + sb[c +  4];
            float t2 = xp[(size_t)(c +  8) * (HH * WW)] + sb[c +  8];
            float t3 = xp[(size_t)(c + 12) * (HH * WW)] + sb[c + 12];
            pk0 |= (t0 > 0.f ? 0x01u : 0xFFu) << (8 * j);
            pk1 |= (t1 > 0.f ? 0x01u : 0xFFu) << (8 * j);
            pk2 |= (t2 > 0.f ? 0x01u : 0xFFu) << (8 * j);
            pk3 |= (t3 > 0.f ? 0x01u : 0xFFu) << (8 * j);
        }
        int4 val = make_int4((int)pk0, (int)pk1, (int)pk2, (int)pk3);
        *(int4*)(S + ((((size_t)b * HP + (h + 1)) * NCG + cg) * HP + (w + 1)) * 16) = val;
    }
}

// 1024 blocks (b*64+h), 256 threads = 4 waves (om = 32-o tile), each wave
// two 32x32 C-tiles (R13 structure, best measured). NEW: explicit tap-level
// A-prefetch ring (a_cur/a_nxt, static indexing -> registers): tap t+1's 8
// global loads are issued BEFORE tap t's 16 ds_read + 16 MFMA (~330 cy),
// covering the ~200 cy L2 latency that serialized every k-step.
__global__ __launch_bounds__(256, 3) void main2_k(
    const signed char* __restrict__ Wt,    // [9][16][128]x16B
    const signed char* __restrict__ S,     // [16][66][16][66]x16B
    const float* __restrict__ x,
    const float* __restrict__ A, const float* __restrict__ B0,
    const float* __restrict__ bias2, const float* __restrict__ bias3,
    const float* __restrict__ prelu_a,
    float* __restrict__ out)
{
    __shared__ v4i Sl[3 * NCG * HP];   // 50688 B
    int bid = blockIdx.x;
    int b = bid >> 6;
    int h = bid & 63;
    int tid = threadIdx.x;
    int l = tid & 63;
    int om = tid >> 6;       // wave-uniform o-tile
    int lr = l & 31;
    int lk = l >> 5;

    // stage rows h..h+2 (contiguous 50688 B in S)
    {
        const v4i* src = (const v4i*)(S + (((size_t)b * HP + h) * NCG) * (size_t)HP * 16);
        #pragma unroll
        for (int i = 0; i < 13; ++i) {
            int idx = tid + i * 256;
            if (idx < 3 * NCG * HP) Sl[idx] = src[idx];
        }
    }
    __syncthreads();

    v16i acc0 = {};
    v16i acc1 = {};

    const signed char* abase = Wt + ((size_t)lk * COUT + om * 32 + lr) * 16;

    // prefetch ring: tap 0
    v4i a_cur[8], a_nxt[8];
    #pragma unroll
    for (int ck = 0; ck < 8; ++ck)
        a_cur[ck] = *(const v4i*)(abase + (size_t)ck * 2 * COUT * 16);

    #pragma unroll
    for (int t = 0; t < 9; ++t) {
        // issue next tap's loads first (8 independent, in flight over MFMAs)
        if (t < 8) {
            const signed char* apn = abase + (size_t)(t + 1) * NCG * COUT * 16;
            #pragma unroll
            for (int ck = 0; ck < 8; ++ck)
                a_nxt[ck] = *(const v4i*)(apn + (size_t)ck * 2 * COUT * 16);
        }
        const int r = t / 3, dw = t % 3;
        const v4i* bl = &Sl[(r * NCG + lk) * HP + dw + lr];
        #pragma unroll
        for (int ck = 0; ck < 8; ++ck) {
            v4i b0 = bl[ck * 2 * HP];
            v4i b1 = bl[ck * 2 * HP + 32];
            acc0 = __builtin_amdgcn_mfma_i32_32x32x32_i8(a_cur[ck], b0, acc0, 0, 0, 0);
            acc1 = __builtin_amdgcn_mfma_i32_32x32x32_i8(a_cur[ck], b1, acc1, 0, 0, 0);
        }
        if (t < 8) {
            #pragma unroll
            for (int ck = 0; ck < 8; ++ck) a_cur[ck] = a_nxt[ck];
        }
    }

    #pragma unroll
    for (int g = 0; g < 16; ++g) {
        int o = om * 32 + (g & 3) + 8 * (g >> 2) + 4 * lk;
        float Ao = A[o], B0o = B0[o];
        float b2 = bias2[b * COUT + o], b3 = bias3[b * COUT + o], pa = prelu_a[o];
        const float* xr = x + ((size_t)(b * CIN + 2 * o)) * (HH * WW) + (size_t)h * WW;
        float* op = out + ((size_t)(b * COUT + o)) * (HH * WW) + (size_t)h * WW;
        {
            int w = lr;
            float cv = (float)acc0[g] * Ao + B0o;
            float r0 = xr[w], r1 = xr[HH * WW + w];
            float tv = cv + 0.5f * (r0 + r1) + b2;
            tv = tv > 0.f ? tv : pa * tv;
            op[w] = tv + b3;
        }
        {
            int w = 32 + lr;
            float cv = (float)acc1[g] * Ao + B0o;
            float r0 = xr[w], r1 = xr[HH * WW + w];
            float tv = cv + 0.5f * (r0 + r1) + b2;
            tv = tv > 0.f ? tv : pa * tv;
            op[w] = tv + b3;
        }
    }
}

extern "C" void kernel_launch(void* const* d_in, const int* in_sizes, int n_in,
                              void* d_out, int out_size, void* d_ws, size_t ws_size,
                              hipStream_t stream) {
    const float* x      = (const float*)d_in[0];
    const float* emb    = (const float*)d_in[1];
    const float* m1w    = (const float*)d_in[2];
    const float* m1b    = (const float*)d_in[3];
    const float* conv_w = (const float*)d_in[4];
    const float* conv_b = (const float*)d_in[5];
    const float* bn_g   = (const float*)d_in[6];
    const float* bn_b   = (const float*)d_in[7];
    const float* bn_m   = (const float*)d_in[8];
    const float* bn_v   = (const float*)d_in[9];
    const float* m2w    = (const float*)d_in[10];
    const float* m2b    = (const float*)d_in[11];
    const float* pa     = (const float*)d_in[12];
    const float* m3w    = (const float*)d_in[13];
    const float* m3b    = (const float*)d_in[14];
    float* out = (float*)d_out;

    char* ws = (char*)d_ws;
    float* bias1 = (float*)(ws + 0);
    float* bias2 = (float*)(ws + 16384);
    float* bias3 = (float*)(ws + 24576);
    float* Aarr  = (float*)(ws + 33280);
    float* B0arr = (float*)(ws + 33792);
    signed char* Wt = (signed char*)(ws + 34304);
    signed char* S  = (signed char*)(ws + 329216);

    prep2_k<<<256, 256, 0, stream>>>(emb, m1w, m1b, m2w, m2b, m3w, m3b,
                                     conv_w, conv_b, bn_g, bn_b, bn_m, bn_v,
                                     bias1, bias2, bias3, Aarr, B0arr, Wt);
    sign_k<<<BB * HH, 256, 0, stream>>>(x, bias1, S);
    main2_k<<<BB * HH, 256, 0, stream>>>(Wt, S, x, Aarr, B0arr,
                                         bias2, bias3, pa, out);
}

// Round 17
// 64.467 us; speedup vs baseline: 1.3090x; 1.0313x over previous
//
#include <hip/hip_runtime.h>

#define BB 16
#define CIN 256
#define COUT 128
#define EE 512
#define HH 64
#define WW 64
#define HP 66   // padded spatial dim
#define NCG 16  // CIN/16 chunks of 16 i8

typedef int v4i __attribute__((ext_vector_type(4)));
typedef int v16i __attribute__((ext_vector_type(16)));

// ws layout (bytes):
//   bias1 [16][256] f32 @ 0        (16384)
//   bias2 [16][128] f32 @ 16384    (8192)
//   bias3 [16][128] f32 @ 24576    (8192)
//   A     [128] f32     @ 33280    (512)
//   B0    [128] f32     @ 33792    (512)
//   Wt2   [9][16][128]x16B @ 34304 (294912)    (tap, c-chunk, o)
//   S2    [16][66][16][66]x16B @ 329216 (17842176)  (b, row, c-chunk, col)
//   R     [16][128][64][64] f16 @ 18171392 (16777216)   (optional, ws-guarded)

__global__ __launch_bounds__(256) void prep2_k(
    const float* __restrict__ emb,
    const float* __restrict__ m1w, const float* __restrict__ m1b,
    const float* __restrict__ m2w, const float* __restrict__ m2b,
    const float* __restrict__ m3w, const float* __restrict__ m3b,
    const float* __restrict__ conv_w, const float* __restrict__ conv_b,
    const float* __restrict__ bn_g, const float* __restrict__ bn_b,
    const float* __restrict__ bn_m, const float* __restrict__ bn_v,
    float* __restrict__ bias1, float* __restrict__ bias2, float* __restrict__ bias3,
    float* __restrict__ A, float* __restrict__ B0,
    signed char* __restrict__ Wt)
{
    int bid = blockIdx.x;
    int tid = threadIdx.x;
    __shared__ float red[256];
    if (bid < 128) {
        int b = bid >> 3;
        int chunk = bid & 7;
        __shared__ float se[EE];
        {
            float v0 = emb[b * EE + tid];
            float v1 = emb[b * EE + tid + 256];
            se[tid] = v0 / (1.0f + __expf(-v0));
            se[tid + 256] = v1 / (1.0f + __expf(-v1));
        }
        __syncthreads();
        int cl = tid & 63;
        int ks = tid >> 6;
        const float* W;
        const float* Bv;
        float* dst;
        int c0;
        if (chunk < 4)      { c0 = chunk * 64;       W = m1w; Bv = m1b; dst = bias1 + b * CIN + c0; }
        else if (chunk < 6) { c0 = (chunk - 4) * 64; W = m2w; Bv = m2b; dst = bias2 + b * COUT + c0; }
        else                { c0 = (chunk - 6) * 64; W = m3w; Bv = m3b; dst = bias3 + b * COUT + c0; }
        const float4* w4 = (const float4*)(W + (size_t)(c0 + cl) * EE + ks * 128);
        const float* sp = &se[ks * 128];
        float acc = 0.f;
        #pragma unroll
        for (int e4 = 0; e4 < 32; ++e4) {
            float4 v = w4[e4];
            acc += sp[e4 * 4 + 0] * v.x + sp[e4 * 4 + 1] * v.y +
                   sp[e4 * 4 + 2] * v.z + sp[e4 * 4 + 3] * v.w;
        }
        red[tid] = acc;
        __syncthreads();
        if (ks == 0)
            dst[cl] = red[cl] + red[cl + 64] + red[cl + 128] + red[cl + 192] + Bv[c0 + cl];
    } else {
        int o = bid - 128;
        int c = tid;
        float wv[9];
        float asum = 0.f;
        const float* wp = conv_w + ((size_t)o * CIN + c) * 9;
        #pragma unroll
        for (int k = 0; k < 9; ++k) {
            float v = wp[k];
            wv[k] = v;
            asum += fabsf(v);
        }
        #pragma unroll
        for (int k = 0; k < 9; ++k)
            Wt[(((size_t)k * NCG + (c >> 4)) * COUT + o) * 16 + (c & 15)] =
                (wv[k] > 0.f) ? (signed char)1 : (signed char)-1;
        red[tid] = asum;
        __syncthreads();
        for (int s = 128; s > 0; s >>= 1) {
            if (tid < s) red[tid] += red[tid + s];
            __syncthreads();
        }
        if (tid == 0) {
            float sc = red[0] * (1.0f / 2304.0f);
            float inv = bn_g[o] * rsqrtf(bn_v[o] + 1e-5f);
            A[o] = sc * inv;
            B0[o] = (conv_b[o] - bn_m[o]) * inv + bn_b[o];
        }
    }
}

// 1024 blocks (b*64+h), 256 threads = 64 w x 4 q-groups; q handles 4 c-chunks.
// Also emits f16 residual R[o] = 0.5*(x[2o]+x[2o+1]) when Rres != null.
__global__ __launch_bounds__(256) void sign_k(
    const float* __restrict__ x, const float* __restrict__ bias1,
    signed char* __restrict__ S, _Float16* __restrict__ Rres)
{
    __shared__ float sb[CIN];
    int bid = blockIdx.x;
    int b = bid >> 6;
    int h = bid & 63;
    int tid = threadIdx.x;

    // halo zeroing: 16 b * 260 ring cells * 16 cg = 66560 16-B chunks
    if (bid < 260) {
        int hidx = bid * 256 + tid;   // exactly 260*256 = 66560
        int cellg = hidx >> 4;
        int cg = hidx & 15;
        int b2 = cellg / 260;
        int rem = cellg % 260;
        int r, col;
        if (rem < 66)       { r = 0;  col = rem; }
        else if (rem < 132) { r = 65; col = rem - 66; }
        else                { int c2 = rem - 132; r = 1 + (c2 >> 1); col = (c2 & 1) * 65; }
        int4 z = make_int4(0, 0, 0, 0);
        *(int4*)(S + ((((size_t)b2 * HP + r) * NCG + cg) * HP + col) * 16) = z;
    }

    sb[tid] = bias1[b * CIN + tid];
    __syncthreads();

    int w = tid & 63;
    int q = tid >> 6;
    const float* xp = x + (size_t)b * CIN * (HH * WW) + (size_t)h * WW + w;
    #pragma unroll
    for (int st = 0; st < 4; ++st) {
        int cg = q * 4 + st;
        float raw[16];
        #pragma unroll
        for (int j = 0; j < 4; ++j) {
            int c = cg * 16 + j;
            raw[j]      = xp[(size_t)(c +  0) * (HH * WW)];
            raw[j + 4]  = xp[(size_t)(c +  4) * (HH * WW)];
            raw[j + 8]  = xp[(size_t)(c +  8) * (HH * WW)];
            raw[j + 12] = xp[(size_t)(c + 12) * (HH * WW)];
        }
        unsigned int pk0 = 0, pk1 = 0, pk2 = 0, pk3 = 0;
        #pragma unroll
        for (int j = 0; j < 4; ++j) {
            int c = cg * 16 + j;
            pk0 |= ((raw[j]      + sb[c]      > 0.f) ? 0x01u : 0xFFu) << (8 * j);
            pk1 |= ((raw[j + 4]  + sb[c + 4]  > 0.f) ? 0x01u : 0xFFu) << (8 * j);
            pk2 |= ((raw[j + 8]  + sb[c + 8]  > 0.f) ? 0x01u : 0xFFu) << (8 * j);
            pk3 |= ((raw[j + 12] + sb[c + 12] > 0.f) ? 0x01u : 0xFFu) << (8 * j);
        }
        int4 val = make_int4((int)pk0, (int)pk1, (int)pk2, (int)pk3);
        *(int4*)(S + ((((size_t)b * HP + (h + 1)) * NCG + cg) * HP + (w + 1)) * 16) = val;
        if (Rres) {
            #pragma unroll
            for (int p = 0; p < 8; ++p) {
                int o = cg * 8 + p;
                Rres[((size_t)(b * COUT + o) * HH + h) * WW + w] =
                    (_Float16)(0.5f * (raw[2 * p] + raw[2 * p + 1]));
            }
        }
    }
}

// 1024 blocks (b*64+h), 256 threads = 4 waves (om = 32-o tile), each wave
// two 32x32 C-tiles (R13 structure). NEW: A double-buffer with inline-asm
// counted s_waitcnt vmcnt(8) + sched_barrier(0) fences — A(t+1)'s 8 loads
// stay in flight across tap t's ds_read+MFMA block; compiler cannot sink
// them (T4 pattern, rules #18/#20).
__global__ __launch_bounds__(256, 3) void main2_k(
    const signed char* __restrict__ Wt,    // [9][16][128]x16B
    const signed char* __restrict__ S,     // [16][66][16][66]x16B
    const float* __restrict__ x,
    const _Float16* __restrict__ Rres,     // nullable
    const float* __restrict__ A, const float* __restrict__ B0,
    const float* __restrict__ bias2, const float* __restrict__ bias3,
    const float* __restrict__ prelu_a,
    float* __restrict__ out)
{
    __shared__ v4i Sl[3 * NCG * HP];   // 50688 B
    int bid = blockIdx.x;
    int b = bid >> 6;
    int h = bid & 63;
    int tid = threadIdx.x;
    int l = tid & 63;
    int om = tid >> 6;       // wave-uniform o-tile
    int lr = l & 31;
    int lk = l >> 5;

    // stage rows h..h+2 (contiguous 50688 B in S)
    {
        const v4i* src = (const v4i*)(S + (((size_t)b * HP + h) * NCG) * (size_t)HP * 16);
        #pragma unroll
        for (int i = 0; i < 13; ++i) {
            int idx = tid + i * 256;
            if (idx < 3 * NCG * HP) Sl[idx] = src[idx];
        }
    }
    __syncthreads();   // drains vmcnt to 0 — staging loads won't pollute counts

    v16i acc0 = {};
    v16i acc1 = {};

    const signed char* abase = Wt + ((size_t)lk * COUT + om * 32 + lr) * 16;

    v4i aA[8], aB[8];
    {   // preload A(0) -> aA
        #pragma unroll
        for (int ck = 0; ck < 8; ++ck)
            aA[ck] = *(const v4i*)(abase + (size_t)ck * 2 * COUT * 16);
    }

    #pragma unroll
    for (int t = 0; t < 9; ++t) {
        if (t < 8) {
            // issue A(t+1) into the spare buffer (8 independent loads)
            const signed char* apn = abase + (size_t)(t + 1) * NCG * COUT * 16;
            if (t & 1) {
                #pragma unroll
                for (int ck = 0; ck < 8; ++ck)
                    aA[ck] = *(const v4i*)(apn + (size_t)ck * 2 * COUT * 16);
            } else {
                #pragma unroll
                for (int ck = 0; ck < 8; ++ck)
                    aB[ck] = *(const v4i*)(apn + (size_t)ck * 2 * COUT * 16);
            }
        }
        __builtin_amdgcn_sched_barrier(0);
        if (t < 8) asm volatile("s_waitcnt vmcnt(8)" ::: "memory");
        else       asm volatile("s_waitcnt vmcnt(0)" ::: "memory");
        __builtin_amdgcn_sched_barrier(0);
        const int r = t / 3, dw = t % 3;
        const v4i* bl = &Sl[(r * NCG + lk) * HP + dw + lr];
        #pragma unroll
        for (int ck = 0; ck < 8; ++ck) {
            v4i b0 = bl[ck * 2 * HP];
            v4i b1 = bl[ck * 2 * HP + 32];
            v4i av = (t & 1) ? aB[ck] : aA[ck];
            acc0 = __builtin_amdgcn_mfma_i32_32x32x32_i8(av, b0, acc0, 0, 0, 0);
            acc1 = __builtin_amdgcn_mfma_i32_32x32x32_i8(av, b1, acc1, 0, 0, 0);
        }
    }

    #pragma unroll
    for (int g = 0; g < 16; ++g) {
        int o = om * 32 + (g & 3) + 8 * (g >> 2) + 4 * lk;
        float Ao = A[o], B0o = B0[o];
        float b2 = bias2[b * COUT + o], b3 = bias3[b * COUT + o], pa = prelu_a[o];
        float* op = out + ((size_t)(b * COUT + o)) * (HH * WW) + (size_t)h * WW;
        if (Rres) {
            const _Float16* rp = Rres + ((size_t)(b * COUT + o) * HH + h) * WW;
            {
                int w = lr;
                float tv = (float)acc0[g] * Ao + B0o + (float)rp[w] + b2;
                tv = tv > 0.f ? tv : pa * tv;
                op[w] = tv + b3;
            }
            {
                int w = 32 + lr;
                float tv = (float)acc1[g] * Ao + B0o + (float)rp[w] + b2;
                tv = tv > 0.f ? tv : pa * tv;
                op[w] = tv + b3;
            }
        } else {
            const float* xr = x + ((size_t)(b * CIN + 2 * o)) * (HH * WW) + (size_t)h * WW;
            {
                int w = lr;
                float tv = (float)acc0[g] * Ao + B0o + 0.5f * (xr[w] + xr[HH * WW + w]) + b2;
                tv = tv > 0.f ? tv : pa * tv;
                op[w] = tv + b3;
            }
            {
                int w = 32 + lr;
                float tv = (float)acc1[g] * Ao + B0o + 0.5f * (xr[w] + xr[HH * WW + w]) + b2;
                tv = tv > 0.f ? tv : pa * tv;
                op[w] = tv + b3;
            }
        }
    }
}

extern "C" void kernel_launch(void* const* d_in, const int* in_sizes, int n_in,
                              void* d_out, int out_size, void* d_ws, size_t ws_size,
                              hipStream_t stream) {
    const float* x      = (const float*)d_in[0];
    const float* emb    = (const float*)d_in[1];
    const float* m1w    = (const float*)d_in[2];
    const float* m1b    = (const float*)d_in[3];
    const float* conv_w = (const float*)d_in[4];
    const float* conv_b = (const float*)d_in[5];
    const float* bn_g   = (const float*)d_in[6];
    const float* bn_b   = (const float*)d_in[7];
    const float* bn_m   = (const float*)d_in[8];
    const float* bn_v   = (const float*)d_in[9];
    const float* m2w    = (const float*)d_in[10];
    const float* m2b    = (const float*)d_in[11];
    const float* pa     = (const float*)d_in[12];
    const float* m3w    = (const float*)d_in[13];
    const float* m3b    = (const float*)d_in[14];
    float* out = (float*)d_out;

    char* ws = (char*)d_ws;
    float* bias1 = (float*)(ws + 0);
    float* bias2 = (float*)(ws + 16384);
    float* bias3 = (float*)(ws + 24576);
    float* Aarr  = (float*)(ws + 33280);
    float* B0arr = (float*)(ws + 33792);
    signed char* Wt = (signed char*)(ws + 34304);
    signed char* S  = (signed char*)(ws + 329216);

    const size_t NEED_R = 18171392ull + (size_t)BB * COUT * HH * WW * 2;  // 34,948,608
    _Float16* Rres = (ws_size >= NEED_R) ? (_Float16*)(ws + 18171392) : (_Float16*)nullptr;

    prep2_k<<<256, 256, 0, stream>>>(emb, m1w, m1b, m2w, m2b, m3w, m3b,
                                     conv_w, conv_b, bn_g, bn_b, bn_m, bn_v,
                                     bias1, bias2, bias3, Aarr, B0arr, Wt);
    sign_k<<<BB * HH, 256, 0, stream>>>(x, bias1, S, Rres);
    main2_k<<<BB * HH, 256, 0, stream>>>(Wt, S, x, Rres, Aarr, B0arr,
                                         bias2, bias3, pa, out);
}